// Round 8
// baseline (192.631 us; speedup 1.0000x reference)
//
#include <hip/hip_runtime.h>
#include <hip/hip_bf16.h>

// AttentionGrouping: B=4096 graphs, N=32 nodes, D=128, H=2 heads.
// Inputs fp32, outputs fp32: out=[B*N,128] then weight=[B*N,32,2] in d_out.
//
// R12: consolidation on the R10 champion (70.6us). R11's bitonic sparsemax
// was neutral (VALU 62->39 but dur +2us: cost moved to LDS-pipe shuffle
// chains) -> revert to R10's broadcast-scan sparsemax. Two deltas:
//  (1) x_l gets its OWN region (t_s 16K + vT_s 16K + x_l 8K = 40960 B):
//      removes the "x_l dead" barrier (5 -> 4 barriers). Ceiling 5->4
//      blocks/CU but measured occupancy (35%) was below the 4-blk ceiling
//      (50%) anyway — the convoy removal is free.
//  (2) s_setprio(1) around MFMA chains (T5: helps when co-resident blocks
//      are at different phases; our 4096 small blocks qualify).

#define NG 4096

typedef short bf16x8 __attribute__((ext_vector_type(8)));
typedef short bf16x4 __attribute__((ext_vector_type(4)));
typedef float f32x4 __attribute__((ext_vector_type(4)));

__device__ inline short f2bf(float f) {
    __hip_bfloat16 h = __float2bfloat16(f);
    return __builtin_bit_cast(short, h);
}
__device__ inline float bf2f(short s) {
    return __builtin_bit_cast(float, ((unsigned)(unsigned short)s) << 16);
}
__device__ inline unsigned pack2(float a, float b) {
    return (unsigned)(unsigned short)f2bf(a) | ((unsigned)(unsigned short)f2bf(b) << 16);
}

// t_s swizzle: [32 node][256 d'] shorts, col ^= (node&7)<<3 (bits 3-5: keeps
// b64/b128 alignment, col stays in [0,256)).
#define TSWZ(node, col) ((((node) << 8)) + (((col) ^ (((node) & 7) << 3))))
// vT_s swizzle: [256 d'][32 node] shorts, idx ^= (row&3)<<3.
#define VSWZ(row, col) ((((row) << 5) + (col)) ^ (((row) & 3) << 3))
// x_l swizzle: [32 node][128 col] shorts, col ^= (node&7)<<3 (col in [0,128)).
#define XSWZ(node, col) (((node) << 7) + (((col) ^ (((node) & 7) << 3))))

// packed_m[(mt*4+s)*512 + lane*8 + jj] = bf16( (1/16)*sum_c WQ[a][h*128+c]*WK[bl][h*128+c] )
//   h = mt>>3, a = s*32+(lane>>4)*8+jj (k-dim of T-mfma), bl = (mt&7)*16+(lane&15)
// A-frag of M^T for T^T = M^T X^T.
// packed_v[(t*4+s)*512 + lane*8 + jj] = bf16(WV[s*32+(lane>>4)*8+jj][t*16+(lane&15)])
// B-frag of WV for V = X WV. Both packs in one launch.
__global__ void pack_mv_kernel(const float* __restrict__ WQ, const float* __restrict__ WK,
                               const float* __restrict__ WV,
                               short* __restrict__ pm, short* __restrict__ pv) {
    int gidx = blockIdx.x * 256 + threadIdx.x;    // 65536 total
    if (gidx < 32768) {
        int idx  = gidx;
        int jj   = idx & 7;
        int lane = (idx >> 3) & 63;
        int s    = (idx >> 9) & 3;
        int mt   = (idx >> 11) & 15;
        int h    = mt >> 3;
        int a    = s * 32 + (lane >> 4) * 8 + jj;
        int bl   = (mt & 7) * 16 + (lane & 15);
        const float4* qa = (const float4*)(WQ + a * 256 + h * 128);
        const float4* kb = (const float4*)(WK + bl * 256 + h * 128);
        float acc = 0.f;
        #pragma unroll 8
        for (int c = 0; c < 32; ++c) {
            float4 q4 = qa[c], k4 = kb[c];
            acc += q4.x * k4.x + q4.y * k4.y + q4.z * k4.z + q4.w * k4.w;
        }
        pm[idx] = f2bf(acc * 0.0625f);
    } else {
        int idx  = gidx - 32768;
        int jj   = idx & 7;
        int lane = (idx >> 3) & 63;
        int s    = (idx >> 9) & 3;
        int t    = (idx >> 11) & 15;
        int krow = s * 32 + (lane >> 4) * 8 + jj;
        int col  = t * 16 + (lane & 15);
        pv[idx] = f2bf(WV[krow * 256 + col]);
    }
}

__global__ __launch_bounds__(256, 4)
void fused_attn_kernel(const float* __restrict__ x, const short* __restrict__ pm,
                       const short* __restrict__ pv, float* __restrict__ out,
                       float* __restrict__ wgt) {
    __shared__ char __align__(16) smem[40960];
    short* t_s  = (short*)smem;               // T [32 node][256 d'] bf16 swz, 16384 B (ph 1a-2a)
    float* s_s  = (float*)smem;               // S [64 row][36 j] f32, 9216 B (ph 2b+) — over dead t_s
    short* vT_s = (short*)(smem + 16384);     // V^T [256 d'][32 node] bf16 swz, 16384 B
    short* x_l  = (short*)(smem + 32768);     // x [32][128] bf16 swz, 8192 B (own region, no alias)

    int b    = blockIdx.x;
    int tid  = threadIdx.x;
    int lane = tid & 63;
    int wave = tid >> 6;
    int lrow = lane & 15;
    int quad = lane >> 4;

    // ---- phase 0: coalesced x -> bf16 x_l (one conversion per element) ----
    const float* xg = x + (size_t)b * 4096;
    #pragma unroll
    for (int i = 0; i < 4; ++i) {
        int flat4 = i * 256 + tid;            // float4 index 0..1023
        int node  = flat4 >> 5;
        int c4    = (flat4 & 31) * 4;
        float4 f  = *(const float4*)&xg[flat4 * 4];
        uint2 pk; pk.x = pack2(f.x, f.y); pk.y = pack2(f.z, f.w);
        *(uint2*)&x_l[XSWZ(node, c4)] = pk;
    }
    __syncthreads();

    // ---- x_l -> register fragments (no second barrier: x_l is not aliased) ----
    bf16x8 xf[2][4];                          // [node-tile][k-chunk]
    #pragma unroll
    for (int nt = 0; nt < 2; ++nt)
        #pragma unroll
        for (int s = 0; s < 4; ++s)
            xf[nt][s] = *(const bf16x8*)&x_l[XSWZ(nt * 16 + lrow, s * 32 + quad * 8)];

    // ---- phase 1a: T^T = M^T X^T -> t_s[node][d'] (swizzled) via packed b64 stores ----
    #pragma unroll
    for (int t = 0; t < 4; ++t) {
        int mt = wave * 4 + t;                // d'-tile 0..15 (head = mt>>3)
        const short* pb = pm + (mt * 4) * 512 + lane * 8;
        bf16x8 wf[4];
        #pragma unroll
        for (int s = 0; s < 4; ++s) wf[s] = *(const bf16x8*)&pb[s * 512];
        f32x4 acc[2] = {{0.f,0.f,0.f,0.f},{0.f,0.f,0.f,0.f}};
        __builtin_amdgcn_s_setprio(1);
        #pragma unroll
        for (int nt = 0; nt < 2; ++nt)
            #pragma unroll
            for (int s = 0; s < 4; ++s)
                acc[nt] = __builtin_amdgcn_mfma_f32_16x16x32_bf16(wf[s], xf[nt][s], acc[nt], 0, 0, 0);
        __builtin_amdgcn_s_setprio(0);
        #pragma unroll
        for (int nt = 0; nt < 2; ++nt) {
            int node = nt * 16 + lrow;
            int addr = TSWZ(node, mt * 16 + quad * 4);
            uint2 pk; pk.x = pack2(acc[nt][0], acc[nt][1]); pk.y = pack2(acc[nt][2], acc[nt][3]);
            *(uint2*)&t_s[addr] = pk;
        }
    }
    // ---- phase 1b: V = X WV -> vT_s[d'][node] (swizzled) via packed b64 stores ----
    #pragma unroll
    for (int t = 0; t < 4; ++t) {
        int ntv = wave * 4 + t;               // d'-col-tile 0..15
        const short* pb = pv + (ntv * 4) * 512 + lane * 8;
        bf16x8 wf[4];
        #pragma unroll
        for (int s = 0; s < 4; ++s) wf[s] = *(const bf16x8*)&pb[s * 512];
        f32x4 acc[2] = {{0.f,0.f,0.f,0.f},{0.f,0.f,0.f,0.f}};
        __builtin_amdgcn_s_setprio(1);
        #pragma unroll
        for (int mt = 0; mt < 2; ++mt)
            #pragma unroll
            for (int s = 0; s < 4; ++s)
                acc[mt] = __builtin_amdgcn_mfma_f32_16x16x32_bf16(xf[mt][s], wf[s], acc[mt], 0, 0, 0);
        __builtin_amdgcn_s_setprio(0);
        #pragma unroll
        for (int mt = 0; mt < 2; ++mt) {
            int row = ntv * 16 + lrow;
            int idx = VSWZ(row, mt * 16 + quad * 4);
            uint2 pk; pk.x = pack2(acc[mt][0], acc[mt][1]); pk.y = pack2(acc[mt][2], acc[mt][3]);
            *(uint2*)&vT_s[idx] = pk;
        }
    }
    __syncthreads();

    // ---- phase 2a: S_h = T_h X^T -> registers. Wave w owns S rows 16w..16w+15
    //      (h = w>>1, it = w&1, both jt halves). ----
    f32x4 sacc[2];
    #pragma unroll
    for (int jt = 0; jt < 2; ++jt) {
        int h = wave >> 1, it = wave & 1;
        f32x4 acc = {0.f, 0.f, 0.f, 0.f};
        __builtin_amdgcn_s_setprio(1);
        #pragma unroll
        for (int s = 0; s < 4; ++s) {
            int node = it * 16 + lrow;
            bf16x8 at = *(const bf16x8*)&t_s[TSWZ(node, h * 128 + s * 32 + quad * 8)];
            acc = __builtin_amdgcn_mfma_f32_16x16x32_bf16(at, xf[jt][s], acc, 0, 0, 0);
        }
        __builtin_amdgcn_s_setprio(0);
        sacc[jt] = acc;
    }
    __syncthreads();                          // t_s dead; s_s may now be written

    // ---- phase 2b: spill own S rows (16w + quad*4 + r) to s_s ----
    #pragma unroll
    for (int jt = 0; jt < 2; ++jt)
        #pragma unroll
        for (int r = 0; r < 4; ++r)
            s_s[(wave * 16 + quad * 4 + r) * 36 + jt * 16 + lrow] = sacc[jt][r];
    // NO barrier: phase 3 reads only wave-own rows (same-wave LDS ordering).

    // ---- phase 3: sparsemax on own 16 rows, tau = max_k (cumsum_k - 1)/k ----
    // Lane (hh=lane>>5, j=lane&31): col j of row 16*wave + hh*8 + ii. Full-row
    // broadcast b128 reads; per-lane rank + strict-greater prefix sum
    // (select+fma, 4 VALU/elem); 5-step shuffle max. Pure scan.
    {
        int j  = lane & 31;
        int hh = lane >> 5;
        #pragma unroll
        for (int ii = 0; ii < 8; ++ii) {
            int row = wave * 16 + hh * 8 + ii;
            const float* zr = &s_s[row * 36];
            float z[32];
            #pragma unroll
            for (int c = 0; c < 8; ++c) {
                float4 f = *(const float4*)&zr[c * 4];
                z[c*4] = f.x; z[c*4+1] = f.y; z[c*4+2] = f.z; z[c*4+3] = f.w;
            }
            float zj = zr[j];
            float c0 = 0.f, c1 = 0.f, s0 = 0.f, s1 = 0.f;
            #pragma unroll
            for (int l = 0; l < 32; l += 2) {
                float m0 = (z[l]     > zj) ? 1.f : 0.f;
                float m1 = (z[l + 1] > zj) ? 1.f : 0.f;
                c0 += m0;  s0 = __builtin_fmaf(m0, z[l],     s0);
                c1 += m1;  s1 = __builtin_fmaf(m1, z[l + 1], s1);
            }
            float rk  = c0 + c1 + 1.f;            // this lane's rank k
            float cum = s0 + s1 + zj;             // cumsum of top-k
            float tc  = (cum - 1.f) / rk;         // tau_k
            #pragma unroll
            for (int m = 1; m <= 16; m <<= 1) tc = fmaxf(tc, __shfl_xor(tc, m, 32));
            float w = fmaxf(zj - tc, 0.f);
            ((short*)zr)[j] = f2bf(w);            // w row aliases S row start
        }
    }
    __syncthreads();

    // ---- phase 4: out = 0.5*(W_0 V_0 + W_1 V_1); wgt writeback from LDS ----
    #pragma unroll
    for (int tt = 0; tt < 4; ++tt) {
        int ti = wave * 4 + tt;               // 0..15 = it(2) x dt(8)
        int it = ti >> 3, dt = ti & 7;
        f32x4 acc = {0.f, 0.f, 0.f, 0.f};
        __builtin_amdgcn_s_setprio(1);
        #pragma unroll
        for (int h = 0; h < 2; ++h) {
            int vrow = h * 128 + dt * 16 + lrow;
            bf16x8 aw = *(const bf16x8*)((short*)&s_s[(h * 32 + it * 16 + lrow) * 36] + quad * 8);
            bf16x8 bv = *(const bf16x8*)&vT_s[VSWZ(vrow, quad * 8)];
            acc = __builtin_amdgcn_mfma_f32_16x16x32_bf16(aw, bv, acc, 0, 0, 0);
        }
        __builtin_amdgcn_s_setprio(0);
        #pragma unroll
        for (int r = 0; r < 4; ++r)
            out[((size_t)b * 32 + it * 16 + quad * 4 + r) * 128 + dt * 16 + lrow] = acc[r] * 0.5f;
    }
    // wgt[node i][j][h]: thread t -> i = t>>3, j = (t&7)*4..+3, both heads.
    {
        int i  = tid >> 3;
        int j2 = (tid & 7) * 4;
        bf16x4 a0 = *(const bf16x4*)((short*)&s_s[i * 36] + j2);         // h=0
        bf16x4 a1 = *(const bf16x4*)((short*)&s_s[(32 + i) * 36] + j2);  // h=1
        float4 o0, o1;
        o0.x = bf2f(a0[0]); o0.y = bf2f(a1[0]); o0.z = bf2f(a0[1]); o0.w = bf2f(a1[1]);
        o1.x = bf2f(a0[2]); o1.y = bf2f(a1[2]); o1.z = bf2f(a0[3]); o1.w = bf2f(a1[3]);
        float* wp = &wgt[((size_t)b * 32 + i) * 64 + j2 * 2];
        *(float4*)wp = o0;
        *(float4*)(wp + 4) = o1;
    }
}

extern "C" void kernel_launch(void* const* d_in, const int* in_sizes, int n_in,
                              void* d_out, int out_size, void* d_ws, size_t ws_size,
                              hipStream_t stream) {
    const float* x  = (const float*)d_in[0];  // [4096,32,128] fp32
    const float* WK = (const float*)d_in[1];  // [128,256] fp32
    const float* WV = (const float*)d_in[2];
    const float* WQ = (const float*)d_in[3];
    float* out = (float*)d_out;               // [131072,128] fp32
    float* wgt = out + (size_t)NG * 32 * 128; // [131072,32,2] fp32
    short* pm = (short*)d_ws;                 // 32768 bf16 = 65536 B
    short* pv = pm + 32768;                   // 32768 bf16 = 65536 B

    hipLaunchKernelGGL(pack_mv_kernel, dim3(256), dim3(256), 0, stream, WQ, WK, WV, pm, pv);
    hipLaunchKernelGGL(fused_attn_kernel, dim3(NG), dim3(256), 0, stream, x, pm, pv, out, wgt);
}

// Round 9
// 183.667 us; speedup vs baseline: 1.0488x; 1.0488x over previous
//
#include <hip/hip_runtime.h>
#include <hip/hip_bf16.h>

// AttentionGrouping: B=4096 graphs, N=32 nodes, D=128, H=2 heads.
// Inputs fp32, outputs fp32: out=[B*N,128] then weight=[B*N,32,2] in d_out.
//
// R13: strict A/B isolation. R12 bundled {x_l own region (barrier 5->4)} +
// {setprio around MFMA} and regressed 70.6->76.5 with VGPR 64->52 — the
// recurring codegen-perturbation signature. setprio is the suspect (m190:
// hurts barrier-synced lockstep waves, which ours are; also acts as a
// codegen boundary shrinking live ranges -> 52 VGPR -> staging serialized).
// R13 = R12 minus ALL setprio = R10 + x_l-own-region only. Primary
// diagnostic: VGPR should return to ~64. Everything else identical to the
// R10 champion (70.6us): scan sparsemax, wave-own spill->scan (no barrier),
// wgt writeback in phase 4.

#define NG 4096

typedef short bf16x8 __attribute__((ext_vector_type(8)));
typedef short bf16x4 __attribute__((ext_vector_type(4)));
typedef float f32x4 __attribute__((ext_vector_type(4)));

__device__ inline short f2bf(float f) {
    __hip_bfloat16 h = __float2bfloat16(f);
    return __builtin_bit_cast(short, h);
}
__device__ inline float bf2f(short s) {
    return __builtin_bit_cast(float, ((unsigned)(unsigned short)s) << 16);
}
__device__ inline unsigned pack2(float a, float b) {
    return (unsigned)(unsigned short)f2bf(a) | ((unsigned)(unsigned short)f2bf(b) << 16);
}

// t_s swizzle: [32 node][256 d'] shorts, col ^= (node&7)<<3 (bits 3-5: keeps
// b64/b128 alignment, col stays in [0,256)).
#define TSWZ(node, col) ((((node) << 8)) + (((col) ^ (((node) & 7) << 3))))
// vT_s swizzle: [256 d'][32 node] shorts, idx ^= (row&3)<<3.
#define VSWZ(row, col) ((((row) << 5) + (col)) ^ (((row) & 3) << 3))
// x_l swizzle: [32 node][128 col] shorts, col ^= (node&7)<<3 (col in [0,128)).
#define XSWZ(node, col) (((node) << 7) + (((col) ^ (((node) & 7) << 3))))

// packed_m[(mt*4+s)*512 + lane*8 + jj] = bf16( (1/16)*sum_c WQ[a][h*128+c]*WK[bl][h*128+c] )
//   h = mt>>3, a = s*32+(lane>>4)*8+jj (k-dim of T-mfma), bl = (mt&7)*16+(lane&15)
// A-frag of M^T for T^T = M^T X^T.
// packed_v[(t*4+s)*512 + lane*8 + jj] = bf16(WV[s*32+(lane>>4)*8+jj][t*16+(lane&15)])
// B-frag of WV for V = X WV. Both packs in one launch.
__global__ void pack_mv_kernel(const float* __restrict__ WQ, const float* __restrict__ WK,
                               const float* __restrict__ WV,
                               short* __restrict__ pm, short* __restrict__ pv) {
    int gidx = blockIdx.x * 256 + threadIdx.x;    // 65536 total
    if (gidx < 32768) {
        int idx  = gidx;
        int jj   = idx & 7;
        int lane = (idx >> 3) & 63;
        int s    = (idx >> 9) & 3;
        int mt   = (idx >> 11) & 15;
        int h    = mt >> 3;
        int a    = s * 32 + (lane >> 4) * 8 + jj;
        int bl   = (mt & 7) * 16 + (lane & 15);
        const float4* qa = (const float4*)(WQ + a * 256 + h * 128);
        const float4* kb = (const float4*)(WK + bl * 256 + h * 128);
        float acc = 0.f;
        #pragma unroll 8
        for (int c = 0; c < 32; ++c) {
            float4 q4 = qa[c], k4 = kb[c];
            acc += q4.x * k4.x + q4.y * k4.y + q4.z * k4.z + q4.w * k4.w;
        }
        pm[idx] = f2bf(acc * 0.0625f);
    } else {
        int idx  = gidx - 32768;
        int jj   = idx & 7;
        int lane = (idx >> 3) & 63;
        int s    = (idx >> 9) & 3;
        int t    = (idx >> 11) & 15;
        int krow = s * 32 + (lane >> 4) * 8 + jj;
        int col  = t * 16 + (lane & 15);
        pv[idx] = f2bf(WV[krow * 256 + col]);
    }
}

__global__ __launch_bounds__(256, 4)
void fused_attn_kernel(const float* __restrict__ x, const short* __restrict__ pm,
                       const short* __restrict__ pv, float* __restrict__ out,
                       float* __restrict__ wgt) {
    __shared__ char __align__(16) smem[40960];
    short* t_s  = (short*)smem;               // T [32 node][256 d'] bf16 swz, 16384 B (ph 1a-2a)
    float* s_s  = (float*)smem;               // S [64 row][36 j] f32, 9216 B (ph 2b+) — over dead t_s
    short* vT_s = (short*)(smem + 16384);     // V^T [256 d'][32 node] bf16 swz, 16384 B
    short* x_l  = (short*)(smem + 32768);     // x [32][128] bf16 swz, 8192 B (own region, no alias)

    int b    = blockIdx.x;
    int tid  = threadIdx.x;
    int lane = tid & 63;
    int wave = tid >> 6;
    int lrow = lane & 15;
    int quad = lane >> 4;

    // ---- phase 0: coalesced x -> bf16 x_l (one conversion per element) ----
    const float* xg = x + (size_t)b * 4096;
    #pragma unroll
    for (int i = 0; i < 4; ++i) {
        int flat4 = i * 256 + tid;            // float4 index 0..1023
        int node  = flat4 >> 5;
        int c4    = (flat4 & 31) * 4;
        float4 f  = *(const float4*)&xg[flat4 * 4];
        uint2 pk; pk.x = pack2(f.x, f.y); pk.y = pack2(f.z, f.w);
        *(uint2*)&x_l[XSWZ(node, c4)] = pk;
    }
    __syncthreads();

    // ---- x_l -> register fragments (no second barrier: x_l is never aliased) ----
    bf16x8 xf[2][4];                          // [node-tile][k-chunk]
    #pragma unroll
    for (int nt = 0; nt < 2; ++nt)
        #pragma unroll
        for (int s = 0; s < 4; ++s)
            xf[nt][s] = *(const bf16x8*)&x_l[XSWZ(nt * 16 + lrow, s * 32 + quad * 8)];

    // ---- phase 1a: T^T = M^T X^T -> t_s[node][d'] (swizzled) via packed b64 stores ----
    #pragma unroll
    for (int t = 0; t < 4; ++t) {
        int mt = wave * 4 + t;                // d'-tile 0..15 (head = mt>>3)
        const short* pb = pm + (mt * 4) * 512 + lane * 8;
        bf16x8 wf[4];
        #pragma unroll
        for (int s = 0; s < 4; ++s) wf[s] = *(const bf16x8*)&pb[s * 512];
        f32x4 acc[2] = {{0.f,0.f,0.f,0.f},{0.f,0.f,0.f,0.f}};
        #pragma unroll
        for (int nt = 0; nt < 2; ++nt)
            #pragma unroll
            for (int s = 0; s < 4; ++s)
                acc[nt] = __builtin_amdgcn_mfma_f32_16x16x32_bf16(wf[s], xf[nt][s], acc[nt], 0, 0, 0);
        #pragma unroll
        for (int nt = 0; nt < 2; ++nt) {
            int node = nt * 16 + lrow;
            int addr = TSWZ(node, mt * 16 + quad * 4);
            uint2 pk; pk.x = pack2(acc[nt][0], acc[nt][1]); pk.y = pack2(acc[nt][2], acc[nt][3]);
            *(uint2*)&t_s[addr] = pk;
        }
    }
    // ---- phase 1b: V = X WV -> vT_s[d'][node] (swizzled) via packed b64 stores ----
    #pragma unroll
    for (int t = 0; t < 4; ++t) {
        int ntv = wave * 4 + t;               // d'-col-tile 0..15
        const short* pb = pv + (ntv * 4) * 512 + lane * 8;
        bf16x8 wf[4];
        #pragma unroll
        for (int s = 0; s < 4; ++s) wf[s] = *(const bf16x8*)&pb[s * 512];
        f32x4 acc[2] = {{0.f,0.f,0.f,0.f},{0.f,0.f,0.f,0.f}};
        #pragma unroll
        for (int mt = 0; mt < 2; ++mt)
            #pragma unroll
            for (int s = 0; s < 4; ++s)
                acc[mt] = __builtin_amdgcn_mfma_f32_16x16x32_bf16(xf[mt][s], wf[s], acc[mt], 0, 0, 0);
        #pragma unroll
        for (int mt = 0; mt < 2; ++mt) {
            int row = ntv * 16 + lrow;
            int idx = VSWZ(row, mt * 16 + quad * 4);
            uint2 pk; pk.x = pack2(acc[mt][0], acc[mt][1]); pk.y = pack2(acc[mt][2], acc[mt][3]);
            *(uint2*)&vT_s[idx] = pk;
        }
    }
    __syncthreads();

    // ---- phase 2a: S_h = T_h X^T -> registers. Wave w owns S rows 16w..16w+15
    //      (h = w>>1, it = w&1, both jt halves). ----
    f32x4 sacc[2];
    #pragma unroll
    for (int jt = 0; jt < 2; ++jt) {
        int h = wave >> 1, it = wave & 1;
        f32x4 acc = {0.f, 0.f, 0.f, 0.f};
        #pragma unroll
        for (int s = 0; s < 4; ++s) {
            int node = it * 16 + lrow;
            bf16x8 at = *(const bf16x8*)&t_s[TSWZ(node, h * 128 + s * 32 + quad * 8)];
            acc = __builtin_amdgcn_mfma_f32_16x16x32_bf16(at, xf[jt][s], acc, 0, 0, 0);
        }
        sacc[jt] = acc;
    }
    __syncthreads();                          // t_s dead; s_s may now be written

    // ---- phase 2b: spill own S rows (16w + quad*4 + r) to s_s ----
    #pragma unroll
    for (int jt = 0; jt < 2; ++jt)
        #pragma unroll
        for (int r = 0; r < 4; ++r)
            s_s[(wave * 16 + quad * 4 + r) * 36 + jt * 16 + lrow] = sacc[jt][r];
    // NO barrier: phase 3 reads only wave-own rows (same-wave LDS ordering).

    // ---- phase 3: sparsemax on own 16 rows, tau = max_k (cumsum_k - 1)/k ----
    // Lane (hh=lane>>5, j=lane&31): col j of row 16*wave + hh*8 + ii. Full-row
    // broadcast b128 reads; per-lane rank + strict-greater prefix sum
    // (select+fma, 4 VALU/elem); 5-step shuffle max. Pure scan.
    {
        int j  = lane & 31;
        int hh = lane >> 5;
        #pragma unroll
        for (int ii = 0; ii < 8; ++ii) {
            int row = wave * 16 + hh * 8 + ii;
            const float* zr = &s_s[row * 36];
            float z[32];
            #pragma unroll
            for (int c = 0; c < 8; ++c) {
                float4 f = *(const float4*)&zr[c * 4];
                z[c*4] = f.x; z[c*4+1] = f.y; z[c*4+2] = f.z; z[c*4+3] = f.w;
            }
            float zj = zr[j];
            float c0 = 0.f, c1 = 0.f, s0 = 0.f, s1 = 0.f;
            #pragma unroll
            for (int l = 0; l < 32; l += 2) {
                float m0 = (z[l]     > zj) ? 1.f : 0.f;
                float m1 = (z[l + 1] > zj) ? 1.f : 0.f;
                c0 += m0;  s0 = __builtin_fmaf(m0, z[l],     s0);
                c1 += m1;  s1 = __builtin_fmaf(m1, z[l + 1], s1);
            }
            float rk  = c0 + c1 + 1.f;            // this lane's rank k
            float cum = s0 + s1 + zj;             // cumsum of top-k
            float tc  = (cum - 1.f) / rk;         // tau_k
            #pragma unroll
            for (int m = 1; m <= 16; m <<= 1) tc = fmaxf(tc, __shfl_xor(tc, m, 32));
            float w = fmaxf(zj - tc, 0.f);
            ((short*)zr)[j] = f2bf(w);            // w row aliases S row start
        }
    }
    __syncthreads();

    // ---- phase 4: out = 0.5*(W_0 V_0 + W_1 V_1); wgt writeback from LDS ----
    #pragma unroll
    for (int tt = 0; tt < 4; ++tt) {
        int ti = wave * 4 + tt;               // 0..15 = it(2) x dt(8)
        int it = ti >> 3, dt = ti & 7;
        f32x4 acc = {0.f, 0.f, 0.f, 0.f};
        #pragma unroll
        for (int h = 0; h < 2; ++h) {
            int vrow = h * 128 + dt * 16 + lrow;
            bf16x8 aw = *(const bf16x8*)((short*)&s_s[(h * 32 + it * 16 + lrow) * 36] + quad * 8);
            bf16x8 bv = *(const bf16x8*)&vT_s[VSWZ(vrow, quad * 8)];
            acc = __builtin_amdgcn_mfma_f32_16x16x32_bf16(aw, bv, acc, 0, 0, 0);
        }
        #pragma unroll
        for (int r = 0; r < 4; ++r)
            out[((size_t)b * 32 + it * 16 + quad * 4 + r) * 128 + dt * 16 + lrow] = acc[r] * 0.5f;
    }
    // wgt[node i][j][h]: thread t -> i = t>>3, j = (t&7)*4..+3, both heads.
    {
        int i  = tid >> 3;
        int j2 = (tid & 7) * 4;
        bf16x4 a0 = *(const bf16x4*)((short*)&s_s[i * 36] + j2);         // h=0
        bf16x4 a1 = *(const bf16x4*)((short*)&s_s[(32 + i) * 36] + j2);  // h=1
        float4 o0, o1;
        o0.x = bf2f(a0[0]); o0.y = bf2f(a1[0]); o0.z = bf2f(a0[1]); o0.w = bf2f(a1[1]);
        o1.x = bf2f(a0[2]); o1.y = bf2f(a1[2]); o1.z = bf2f(a0[3]); o1.w = bf2f(a1[3]);
        float* wp = &wgt[((size_t)b * 32 + i) * 64 + j2 * 2];
        *(float4*)wp = o0;
        *(float4*)(wp + 4) = o1;
    }
}

extern "C" void kernel_launch(void* const* d_in, const int* in_sizes, int n_in,
                              void* d_out, int out_size, void* d_ws, size_t ws_size,
                              hipStream_t stream) {
    const float* x  = (const float*)d_in[0];  // [4096,32,128] fp32
    const float* WK = (const float*)d_in[1];  // [128,256] fp32
    const float* WV = (const float*)d_in[2];
    const float* WQ = (const float*)d_in[3];
    float* out = (float*)d_out;               // [131072,128] fp32
    float* wgt = out + (size_t)NG * 32 * 128; // [131072,32,2] fp32
    short* pm = (short*)d_ws;                 // 32768 bf16 = 65536 B
    short* pv = pm + 32768;                   // 32768 bf16 = 65536 B

    hipLaunchKernelGGL(pack_mv_kernel, dim3(256), dim3(256), 0, stream, WQ, WK, WV, pm, pv);
    hipLaunchKernelGGL(fused_attn_kernel, dim3(NG), dim3(256), 0, stream, x, pm, pv, out, wgt);
}